// Round 10
// baseline (839.222 us; speedup 1.0000x reference)
//
#include <hip/hip_runtime.h>
#include <math.h>

#define NN 100000
#define E0E 1600000
#define EE (E0E + NN)
#define NEG 0.2f
#define BNEPS 1e-5f
#define LOG2E 1.4426950408889634f

typedef float f4 __attribute__((ext_vector_type(4)));
typedef float f2 __attribute__((ext_vector_type(2)));
typedef short s8v __attribute__((ext_vector_type(8)));

__device__ __forceinline__ float wred_max(float v) {
#pragma unroll
  for (int m = 1; m < 64; m <<= 1) v = fmaxf(v, __shfl_xor(v, m, 64));
  return v;
}
__device__ __forceinline__ float wred_sum(float v) {
#pragma unroll
  for (int m = 1; m < 64; m <<= 1) v += __shfl_xor(v, m, 64);
  return v;
}
__device__ __forceinline__ float sel4(float a0, float a1, float a2, float a3, int hd) {
  return (hd & 2) ? ((hd & 1) ? a3 : a2) : ((hd & 1) ? a1 : a0);
}
__device__ __forceinline__ unsigned short f2bf(float x) {  // RNE
  unsigned u = __float_as_uint(x);
  return (unsigned short)((u + 0x7fffu + ((u >> 16) & 1u)) >> 16);
}
__device__ __forceinline__ float bf2f(unsigned short s) {
  return __uint_as_float(((unsigned)s) << 16);
}
// async global->LDS, 16B per lane; LDS dest = wave-uniform base + lane*16
__device__ __forceinline__ void gll16(const void* g, void* l) {
  __builtin_amdgcn_global_load_lds(
      (const __attribute__((address_space(1))) void*)g,
      (__attribute__((address_space(3))) void*)l, 16, 0, 0);
}

// ---------------- CSR build ----------------
__global__ void k_count(const int* __restrict__ col, int* cnt, int e) {
  int i = blockIdx.x * blockDim.x + threadIdx.x;
  if (i < e) atomicAdd(&cnt[col[i]], 1);
}
#define SCAN_T 1024
__global__ void k_scan1(const int* __restrict__ cnt, int* partial, int n, int chunk) {
  int i = blockIdx.x * blockDim.x + threadIdx.x;
  int beg = i * chunk, end = min(n, beg + chunk);
  int s = 0;
  for (int j = beg; j < end; ++j) s += cnt[j];
  partial[i] = s;
}
__global__ void k_scan2(int* partial) {
  __shared__ int lds[SCAN_T];
  int t = threadIdx.x;
  int v = partial[t];
  lds[t] = v;
  __syncthreads();
  for (int off = 1; off < SCAN_T; off <<= 1) {
    int add = (t >= off) ? lds[t - off] : 0;
    __syncthreads();
    lds[t] += add;
    __syncthreads();
  }
  partial[t] = lds[t] - v;  // exclusive
}
__global__ void k_scan3(const int* __restrict__ cnt, const int* __restrict__ partial,
                        int* rowptr, int* cursor, int n, int chunk, int etot) {
  int i = blockIdx.x * blockDim.x + threadIdx.x;
  int beg = i * chunk, end = min(n, beg + chunk);
  int run = partial[i];
  for (int j = beg; j < end; ++j) {
    rowptr[j] = run;
    cursor[j] = run;
    run += cnt[j];
  }
  if (i == SCAN_T - 1) rowptr[n] = etot;
}
__global__ void k_scatter(const int* __restrict__ row, const int* __restrict__ col,
                          const float* __restrict__ ea, int* cursor, int2* csr, int e) {
  int i = blockIdx.x * blockDim.x + threadIdx.x;
  if (i < e) {
    int c = col[i];
    int p = atomicAdd(&cursor[c], 1);
    csr[p] = make_int2(row[i], __float_as_int(ea[i]));
  }
}

// ---------------- BatchNorm stats (bf16 input) ----------------
__global__ void k_bnstats(const unsigned short* __restrict__ x, double* sums, int n) {
  int f = threadIdx.x & 63;
  int rt = (blockIdx.x * blockDim.x + threadIdx.x) >> 6;
  int rstride = (gridDim.x * blockDim.x) >> 6;
  double s = 0.0, q = 0.0;
  for (int r = rt; r < n; r += rstride) {
    double v = (double)bf2f(x[(size_t)r * 64 + f]);
    s += v;
    q += v * v;
  }
  __shared__ double ls[256], lq[256];
  ls[threadIdx.x] = s;
  lq[threadIdx.x] = q;
  __syncthreads();
  if (threadIdx.x < 64) {
    s = ls[threadIdx.x] + ls[threadIdx.x + 64] + ls[threadIdx.x + 128] + ls[threadIdx.x + 192];
    q = lq[threadIdx.x] + lq[threadIdx.x + 64] + lq[threadIdx.x + 128] + lq[threadIdx.x + 192];
    atomicAdd(&sums[f], s);
    atomicAdd(&sums[64 + f], q);
  }
}

// ---------------- weight prep (parallel): fused BN-final + fold + bf16 -------
__global__ void k_prepw(const float* __restrict__ W, const double* __restrict__ bnsum,
                        const float* __restrict__ gamma, const float* __restrict__ beta,
                        const float* __restrict__ bin, unsigned short* __restrict__ Wt,
                        float* __restrict__ cvec, int K, int N, int mode) {
  __shared__ float ABl[128];
  __shared__ float cred[4][64];
  int t = threadIdx.x;
  if (mode == 1) {
    if (t < 64) {
      double mean = bnsum[t] / NN;
      double var = bnsum[64 + t] / NN - mean * mean;
      float A = gamma[t] * rsqrtf((float)var + BNEPS);
      ABl[t] = A;
      ABl[64 + t] = beta[t] - (float)mean * A;
    }
    __syncthreads();
  }
  int cl = t & 63, kq = t >> 6;
  int col = blockIdx.x * 64 + cl;
  int kn = K >> 2;
  int k0 = kq * kn;
  float c = 0.f;
#pragma unroll 8
  for (int k = k0; k < k0 + kn; ++k) {
    float w = W[k * N + col];
    float a = 1.f, b = 0.f;
    if (mode == 1) { a = ABl[k]; b = ABl[64 + k]; }
    Wt[col * K + k] = f2bf(a * w);
    c = fmaf(b, w, c);
  }
  cred[kq][cl] = c;
  __syncthreads();
  if (kq == 0) {
    float cc = cred[0][cl] + cred[1][cl] + cred[2][cl] + cred[3][cl];
    if (mode == 2) cc += bin[col];
    cvec[col] = cc;
  }
}

// ---------------- MFMA GEMM: h = x @ W' (+c), att scores --------------------
// INBF path stages via global_load_lds (linear LDS dest, pre-swizzled source).
template <int K, int CT, bool ATT, bool OB, bool INBF>
__global__ __launch_bounds__(256, 2) void k_gemm(const void* __restrict__ xv,
                                                 const unsigned short* __restrict__ Wt,
                                                 const float* __restrict__ cvec,
                                                 const float* __restrict__ att,
                                                 void* __restrict__ houtv,
                                                 float* __restrict__ s_i,
                                                 float* __restrict__ s_j, int n,
                                                 int ntiles) {
  constexpr int KS = K / 32;
  constexpr int ROWB = 2 * K;
  constexpr int CPR = K / 8;  // 16B chunks per row
  constexpr int NCOL = 4 * CT * 16;
  __shared__ unsigned char xs[64 * ROWB];
  const int lane = threadIdx.x & 63;
  const int wv = threadIdx.x >> 6;
  const int l15 = lane & 15;
  const int lq = lane >> 4;
  const int colbase = wv * CT * 16;

  s8v wfr[CT][KS];
#pragma unroll
  for (int ct = 0; ct < CT; ++ct)
#pragma unroll
    for (int ks = 0; ks < KS; ++ks)
      wfr[ct][ks] = *(const s8v*)&Wt[(size_t)(colbase + ct * 16 + l15) * K + ks * 32 + lq * 8];
  float cb[CT][4];
#pragma unroll
  for (int ct = 0; ct < CT; ++ct)
#pragma unroll
    for (int r = 0; r < 4; ++r) cb[ct][r] = cvec[colbase + ct * 16 + lq * 4 + r];
  float ati[ATT ? CT : 1][4], atj[ATT ? CT : 1][4];
  if constexpr (ATT) {
    const float* ar = att + wv * 129;
#pragma unroll
    for (int ct = 0; ct < CT; ++ct)
#pragma unroll
      for (int r = 0; r < 4; ++r) {
        int cc = ct * 16 + lq * 4 + r;
        ati[ct][r] = ar[cc];
        atj[ct][r] = ar[64 + cc];
      }
  }

  for (int t = blockIdx.x; t < ntiles; t += gridDim.x) {
    const int row0 = t * 64;
    __syncthreads();
    if constexpr (INBF) {
      // async staging: LDS linear (wave base + lane*16); swizzle on global src.
      const unsigned char* xin8 = (const unsigned char*)xv;
#pragma unroll
      for (int i = 0; i < (64 * CPR) / 256; ++i) {
        int cbase = i * 256 + wv * 64;  // wave-uniform chunk base
        int c = cbase + lane;
        int row = c / CPR, kc = c % CPR;
        int rg = min(row0 + row, n - 1);
        int swz = kc ^ (row & 7);  // CPR==8 -> full-range XOR (matches read path)
        gll16(xin8 + (size_t)rg * ROWB + swz * 16, &xs[cbase * 16]);
      }
    } else {
#pragma unroll
      for (int i = 0; i < (64 * CPR) / 256; ++i) {
        int c = threadIdx.x + i * 256;
        int row = c / CPR, kc = c % CPR;
        int rg = min(row0 + row, n - 1);
        int dst = row * ROWB + ((kc * 16) ^ ((row & 7) << 4));
        const float* xin = (const float*)xv;
        const float* xp = xin + (size_t)rg * K + kc * 8;
        f4 a0 = *(const f4*)xp;
        f4 a1 = *(const f4*)(xp + 4);
        union { s8v v; unsigned short u[8]; } pk;
        pk.u[0] = f2bf(a0[0]); pk.u[1] = f2bf(a0[1]); pk.u[2] = f2bf(a0[2]); pk.u[3] = f2bf(a0[3]);
        pk.u[4] = f2bf(a1[0]); pk.u[5] = f2bf(a1[1]); pk.u[6] = f2bf(a1[2]); pk.u[7] = f2bf(a1[3]);
        *(s8v*)&xs[dst] = pk.v;
      }
    }
    __syncthreads();
    f4 acc[4][CT];
#pragma unroll
    for (int rt = 0; rt < 4; ++rt)
#pragma unroll
      for (int ct = 0; ct < CT; ++ct) acc[rt][ct] = (f4)0.f;
#pragma unroll
    for (int ks = 0; ks < KS; ++ks) {
      s8v xf[4];
#pragma unroll
      for (int rt = 0; rt < 4; ++rt) {
        int row = rt * 16 + l15;
        int kb = ks * 64 + lq * 16;
        xf[rt] = *(const s8v*)&xs[row * ROWB + (kb ^ ((row & 7) << 4))];
      }
#pragma unroll
      for (int rt = 0; rt < 4; ++rt)
#pragma unroll
        for (int ct = 0; ct < CT; ++ct)
          acc[rt][ct] = __builtin_amdgcn_mfma_f32_16x16x32_bf16(wfr[ct][ks], xf[rt],
                                                                acc[rt][ct], 0, 0, 0);
    }
#pragma unroll
    for (int rt = 0; rt < 4; ++rt) {
      if (row0 + rt * 16 >= n) continue;
      const size_t xrow = (size_t)(row0 + rt * 16 + l15);
      float v[CT][4];
#pragma unroll
      for (int ct = 0; ct < CT; ++ct)
#pragma unroll
        for (int r = 0; r < 4; ++r) v[ct][r] = acc[rt][ct][r] + cb[ct][r];
      if constexpr (OB) {
        float* outp = (float*)houtv;
#pragma unroll
        for (int ct = 0; ct < CT; ++ct) {
          f4 o;
          o[0] = v[ct][0]; o[1] = v[ct][1]; o[2] = v[ct][2]; o[3] = v[ct][3];
          *(f4*)&outp[xrow * NCOL + colbase + ct * 16 + lq * 4] = o;
        }
      } else {
        unsigned short* hout = (unsigned short*)houtv;
#pragma unroll
        for (int ct = 0; ct < CT; ++ct) {
          ushort4 hb4;
          hb4.x = f2bf(v[ct][0]); hb4.y = f2bf(v[ct][1]);
          hb4.z = f2bf(v[ct][2]); hb4.w = f2bf(v[ct][3]);
          *(ushort4*)&hout[xrow * NCOL + colbase + ct * 16 + lq * 4] = hb4;
        }
      }
      if constexpr (ATT) {
        float pi = 0.f, pj = 0.f;
#pragma unroll
        for (int ct = 0; ct < CT; ++ct)
#pragma unroll
          for (int r = 0; r < 4; ++r) {
            pi = fmaf(v[ct][r], ati[ct][r], pi);
            pj = fmaf(v[ct][r], atj[ct][r], pj);
          }
        pi += __shfl_xor(pi, 16, 64); pi += __shfl_xor(pi, 32, 64);
        pj += __shfl_xor(pj, 16, 64); pj += __shfl_xor(pj, 32, 64);
        if (lane < 16) {
          s_i[xrow * 4 + wv] = pi;
          s_j[xrow * 4 + wv] = pj;
        }
      }
    }
  }
}

// ---------------- edge softmax + aggregate (R9-frozen) ----------------------
__global__ __launch_bounds__(256) void k_edge(const int* __restrict__ rowptr,
                                              const int2* __restrict__ csr,
                                              const float* __restrict__ s_i,
                                              const float* __restrict__ s_j,
                                              const unsigned short* __restrict__ hb,
                                              const float* __restrict__ linE,
                                              const float* __restrict__ att,
                                              const float* __restrict__ bias,
                                              unsigned short* __restrict__ xout, int n) {
  __shared__ float lp[4][64][4];
  __shared__ int lsrc[4][64];  // byte offsets into hb
  const unsigned char* hb8 = (const unsigned char*)hb;
  const int lane = threadIdx.x & 63;
  const int wid = threadIdx.x >> 6;
  const int lane8 = lane * 8;
  int v = blockIdx.x * 4 + wid;
  if (v >= n) return;
  v = __builtin_amdgcn_readfirstlane(v);
  const int base = rowptr[v];
  const int deg = rowptr[v + 1] - base;

  const float coef0 = linE[0] * att[0 * 129 + 128];
  const float coef1 = linE[1] * att[1 * 129 + 128];
  const float coef2 = linE[2] * att[2 * 129 + 128];
  const float coef3 = linE[3] * att[3 * 129 + 128];
  const float sj0 = s_j[(size_t)v * 4 + 0];
  const float sj1 = s_j[(size_t)v * 4 + 1];
  const float sj2 = s_j[(size_t)v * 4 + 2];
  const float sj3 = s_j[(size_t)v * 4 + 3];

  auto edge_logits = [&](int i, int& src, float& g0, float& g1, float& g2, float& g3) {
    int2 pk = csr[i];
    src = pk.x;
    float ea = __int_as_float(pk.y);
    f4 siv = *(const f4*)&s_i[(size_t)src * 4];
    g0 = siv[0] + sj0 + ea * coef0; g0 = fmaxf(g0, g0 * NEG);
    g1 = siv[1] + sj1 + ea * coef1; g1 = fmaxf(g1, g1 * NEG);
    g2 = siv[2] + sj2 + ea * coef2; g2 = fmaxf(g2, g2 * NEG);
    g3 = siv[3] + sj3 + ea * coef3; g3 = fmaxf(g3, g3 * NEG);
  };

  const int hd = lane >> 4;
  f4 acc;
  {
    ushort4 hr = *(const ushort4*)(hb8 + ((unsigned)v << 9) + lane8);
    acc[0] = bf2f(hr.x); acc[1] = bf2f(hr.y); acc[2] = bf2f(hr.z); acc[3] = bf2f(hr.w);
  }

  bool fast = (deg <= 64);
  if (fast) {
    float g0 = -INFINITY, g1 = -INFINITY, g2 = -INFINITY, g3 = -INFINITY;
    int src = 0;
    bool valid = lane < deg;
    if (valid) edge_logits(base + lane, src, g0, g1, g2, g3);
    float m0 = wred_max(g0), m1 = wred_max(g1), m2 = wred_max(g2), m3 = wred_max(g3);
    float p0 = valid ? exp2f((g0 - m0) * LOG2E) : 0.f;
    float p1 = valid ? exp2f((g1 - m1) * LOG2E) : 0.f;
    float p2 = valid ? exp2f((g2 - m2) * LOG2E) : 0.f;
    float p3 = valid ? exp2f((g3 - m3) * LOG2E) : 0.f;
    float d0 = wred_sum(p0), d1 = wred_sum(p1), d2 = wred_sum(p2), d3 = wred_sum(p3);
    float rd0 = 1.f / (d0 + 1e-16f);
    float rd1 = 1.f / (d1 + 1e-16f);
    float rd2 = 1.f / (d2 + 1e-16f);
    float rd3 = 1.f / (d3 + 1e-16f);
    if (valid) {
      f4 pp;
      pp[0] = p0 * rd0; pp[1] = p1 * rd1; pp[2] = p2 * rd2; pp[3] = p3 * rd3;
      *(f4*)&lp[wid][lane][0] = pp;
      lsrc[wid][lane] = src << 9;
    }
    for (int e = 0; e < deg; ++e) {
      int off = lsrc[wid][e];
      float a = lp[wid][e][hd];
      ushort4 h0 = *(const ushort4*)(hb8 + (unsigned)(off + lane8));
      acc[0] = fmaf(a, bf2f(h0.x), acc[0]);
      acc[1] = fmaf(a, bf2f(h0.y), acc[1]);
      acc[2] = fmaf(a, bf2f(h0.z), acc[2]);
      acc[3] = fmaf(a, bf2f(h0.w), acc[3]);
    }
  } else {
    float m0 = -INFINITY, m1 = -INFINITY, m2 = -INFINITY, m3 = -INFINITY;
    for (int c0 = 0; c0 < deg; c0 += 64) {
      int i = c0 + lane;
      if (i < deg) {
        int src; float g0, g1, g2, g3;
        edge_logits(base + i, src, g0, g1, g2, g3);
        m0 = fmaxf(m0, g0); m1 = fmaxf(m1, g1); m2 = fmaxf(m2, g2); m3 = fmaxf(m3, g3);
      }
    }
    m0 = wred_max(m0); m1 = wred_max(m1); m2 = wred_max(m2); m3 = wred_max(m3);
    float d0 = 0, d1 = 0, d2 = 0, d3 = 0;
    for (int c0 = 0; c0 < deg; c0 += 64) {
      int i = c0 + lane;
      if (i < deg) {
        int src; float g0, g1, g2, g3;
        edge_logits(base + i, src, g0, g1, g2, g3);
        d0 += exp2f((g0 - m0) * LOG2E);
        d1 += exp2f((g1 - m1) * LOG2E);
        d2 += exp2f((g2 - m2) * LOG2E);
        d3 += exp2f((g3 - m3) * LOG2E);
      }
    }
    d0 = wred_sum(d0); d1 = wred_sum(d1); d2 = wred_sum(d2); d3 = wred_sum(d3);
    float msel = sel4(m0, m1, m2, m3, hd);
    float rdsel = 1.f / (sel4(d0, d1, d2, d3, hd) + 1e-16f);
    const float sjsel = sel4(sj0, sj1, sj2, sj3, hd);
    const float cfsel = sel4(coef0, coef1, coef2, coef3, hd);
    for (int e = base; e < base + deg; ++e) {
      int2 pk = csr[e];
      int src = pk.x;
      float ea = __int_as_float(pk.y);
      f4 siv = *(const f4*)&s_i[(size_t)src * 4];
      float lg = sel4(siv[0], siv[1], siv[2], siv[3], hd) + sjsel + ea * cfsel;
      lg = fmaxf(lg, lg * NEG);
      float a = exp2f((lg - msel) * LOG2E) * rdsel;
      ushort4 hr = *(const ushort4*)(hb8 + ((unsigned)src << 9) + lane8);
      acc[0] = fmaf(a, bf2f(hr.x), acc[0]);
      acc[1] = fmaf(a, bf2f(hr.y), acc[1]);
      acc[2] = fmaf(a, bf2f(hr.z), acc[2]);
      acc[3] = fmaf(a, bf2f(hr.w), acc[3]);
    }
  }
#pragma unroll
  for (int m = 16; m < 64; m <<= 1) {
    acc[0] += __shfl_xor(acc[0], m, 64);
    acc[1] += __shfl_xor(acc[1], m, 64);
    acc[2] += __shfl_xor(acc[2], m, 64);
    acc[3] += __shfl_xor(acc[3], m, 64);
  }
  if (lane < 16) {
    f4 bv = *(const f4*)&bias[lane * 4];
    ushort4 o;
    o.x = f2bf(fmaxf(acc[0] * 0.25f + bv[0], 0.f));
    o.y = f2bf(fmaxf(acc[1] * 0.25f + bv[1], 0.f));
    o.z = f2bf(fmaxf(acc[2] * 0.25f + bv[2], 0.f));
    o.w = f2bf(fmaxf(acc[3] * 0.25f + bv[3], 0.f));
    *(ushort4*)&xout[(size_t)v * 64 + lane * 4] = o;
  }
}

// ---------------- host launch ----------------
extern "C" void kernel_launch(void* const* d_in, const int* in_sizes, int n_in,
                              void* d_out, int out_size, void* d_ws, size_t ws_size,
                              hipStream_t stream) {
  const float* x_in = (const float*)d_in[0];
  const int* ei = (const int*)d_in[1];
  const float* eattr = (const float*)d_in[2];
  const float* linN0 = (const float*)d_in[3];
  const float* linNr = (const float*)d_in[4];
  const float* linE = (const float*)d_in[5];
  const float* attA = (const float*)d_in[6];
  const float* biasA = (const float*)d_in[7];
  const float* bng = (const float*)d_in[8];
  const float* bnb = (const float*)d_in[9];
  const float* W = (const float*)d_in[10];
  const float* bb = (const float*)d_in[11];
  float* out = (float*)d_out;

  const int* row = ei;
  const int* col = ei + EE;

  char* ws = (char*)d_ws;
  size_t o = 0;
  auto alloc = [&](size_t bytes) {
    void* p = ws + o;
    o += (bytes + 255) & ~(size_t)255;
    return p;
  };
  int* cnt = (int*)alloc((size_t)NN * 4);
  int* cursor = (int*)alloc((size_t)NN * 4);
  int* rowptr = (int*)alloc((size_t)(NN + 1) * 4);
  int* partial = (int*)alloc((size_t)SCAN_T * 4);
  int2* csr = (int2*)alloc((size_t)EE * 8);
  unsigned short* h = (unsigned short*)alloc((size_t)NN * 256 * 2);   // bf16
  float* si = (float*)alloc((size_t)NN * 4 * 4);
  float* sj = (float*)alloc((size_t)NN * 4 * 4);
  unsigned short* xa = (unsigned short*)alloc((size_t)NN * 64 * 2);   // bf16
  unsigned short* xb = (unsigned short*)alloc((size_t)NN * 64 * 2);   // bf16
  double* bnsum = (double*)alloc(256 * 8);
  unsigned short* Wt = (unsigned short*)alloc((size_t)256 * 128 * 2);
  unsigned short* Wt2 = (unsigned short*)alloc((size_t)128 * 64 * 2);
  float* cvec = (float*)alloc(256 * 4);
  float* cvec2 = (float*)alloc(256 * 4);
  if (o > ws_size) return;

  const int chunk = (NN + SCAN_T - 1) / SCAN_T;
  const int NTILES = (NN + 63) / 64;  // 1563
  const int GG = 512;                  // 2 blocks/CU resident, ~3 tiles each

  hipMemsetAsync(cnt, 0, (size_t)NN * 4, stream);
  hipMemsetAsync(bnsum, 0, 256 * 8, stream);
  k_count<<<(EE + 255) / 256, 256, 0, stream>>>(col, cnt, EE);
  k_scan1<<<4, 256, 0, stream>>>(cnt, partial, NN, chunk);
  k_scan2<<<1, SCAN_T, 0, stream>>>(partial);
  k_scan3<<<4, 256, 0, stream>>>(cnt, partial, rowptr, cursor, NN, chunk, EE);
  k_scatter<<<(EE + 255) / 256, 256, 0, stream>>>(row, col, eattr, cursor, csr, EE);
  // final-W prep early (input-only dependency)
  k_prepw<<<2, 256, 0, stream>>>(W, nullptr, nullptr, nullptr, bb, Wt2, cvec2, 64, 128, 2);

  // ---- layer 0 ----
  k_prepw<<<4, 256, 0, stream>>>(linN0, nullptr, nullptr, nullptr, nullptr, Wt, cvec, 128, 256, 0);
  k_gemm<128, 4, true, false, false><<<GG, 256, 0, stream>>>(x_in, Wt, cvec, attA + 0,
                                                             h, si, sj, NN, NTILES);
  k_edge<<<NN / 4, 256, 0, stream>>>(rowptr, csr, si, sj, h, linE + 0, attA + 0, biasA + 0,
                                     xa, NN);

  // ---- layer 1 ----
  k_bnstats<<<256, 256, 0, stream>>>(xa, bnsum, NN);
  k_prepw<<<4, 256, 0, stream>>>(linNr, bnsum, bng, bnb, nullptr, Wt, cvec, 64, 256, 1);
  k_gemm<64, 4, true, false, true><<<GG, 256, 0, stream>>>(xa, Wt, cvec, attA + 516,
                                                           h, si, sj, NN, NTILES);
  k_edge<<<NN / 4, 256, 0, stream>>>(rowptr, csr, si, sj, h, linE + 4, attA + 516, biasA + 64,
                                     xb, NN);

  // ---- layer 2 ----
  k_bnstats<<<256, 256, 0, stream>>>(xb, bnsum + 128, NN);
  k_prepw<<<4, 256, 0, stream>>>(linNr + 64 * 256, bnsum + 128, bng + 64, bnb + 64, nullptr,
                                 Wt, cvec, 64, 256, 1);
  k_gemm<64, 4, true, false, true><<<GG, 256, 0, stream>>>(xb, Wt, cvec, attA + 2 * 516,
                                                           h, si, sj, NN, NTILES);
  k_edge<<<NN / 4, 256, 0, stream>>>(rowptr, csr, si, sj, h, linE + 8, attA + 2 * 516,
                                     biasA + 128, xa, NN);

  // ---- final linear ----
  k_gemm<64, 2, false, true, true><<<GG, 256, 0, stream>>>(xa, Wt2, cvec2, nullptr, out,
                                                           nullptr, nullptr, NN, NTILES);
}

// Round 11
// 828.945 us; speedup vs baseline: 1.0124x; 1.0124x over previous
//
#include <hip/hip_runtime.h>
#include <math.h>

#define NN 100000
#define E0E 1600000
#define EE (E0E + NN)
#define NEG 0.2f
#define BNEPS 1e-5f
#define LOG2E 1.4426950408889634f

typedef float f4 __attribute__((ext_vector_type(4)));
typedef short s8v __attribute__((ext_vector_type(8)));

__device__ __forceinline__ float wred_max(float v) {
#pragma unroll
  for (int m = 1; m < 64; m <<= 1) v = fmaxf(v, __shfl_xor(v, m, 64));
  return v;
}
__device__ __forceinline__ float wred_sum(float v) {
#pragma unroll
  for (int m = 1; m < 64; m <<= 1) v += __shfl_xor(v, m, 64);
  return v;
}
__device__ __forceinline__ float sel4(float a0, float a1, float a2, float a3, int hd) {
  return (hd & 2) ? ((hd & 1) ? a3 : a2) : ((hd & 1) ? a1 : a0);
}
__device__ __forceinline__ unsigned short f2bf(float x) {  // RNE
  unsigned u = __float_as_uint(x);
  return (unsigned short)((u + 0x7fffu + ((u >> 16) & 1u)) >> 16);
}
__device__ __forceinline__ float bf2f(unsigned short s) {
  return __uint_as_float(((unsigned)s) << 16);
}
// async global->LDS, 16B per lane; LDS dest = wave-uniform base + lane*16
__device__ __forceinline__ void gll16(const void* g, void* l) {
  __builtin_amdgcn_global_load_lds(
      (const __attribute__((address_space(1))) void*)g,
      (__attribute__((address_space(3))) void*)l, 16, 0, 0);
}

// ---------------- CSR build ----------------
__global__ void k_count(const int* __restrict__ col, int* cnt, int e) {
  int i = blockIdx.x * blockDim.x + threadIdx.x;
  if (i < e) atomicAdd(&cnt[col[i]], 1);
}
#define SCAN_T 1024
__global__ void k_scan1(const int* __restrict__ cnt, int* partial, int n, int chunk) {
  int i = blockIdx.x * blockDim.x + threadIdx.x;
  int beg = i * chunk, end = min(n, beg + chunk);
  int s = 0;
  for (int j = beg; j < end; ++j) s += cnt[j];
  partial[i] = s;
}
__global__ void k_scan2(int* partial) {
  __shared__ int lds[SCAN_T];
  int t = threadIdx.x;
  int v = partial[t];
  lds[t] = v;
  __syncthreads();
  for (int off = 1; off < SCAN_T; off <<= 1) {
    int add = (t >= off) ? lds[t - off] : 0;
    __syncthreads();
    lds[t] += add;
    __syncthreads();
  }
  partial[t] = lds[t] - v;  // exclusive
}
__global__ void k_scan3(const int* __restrict__ cnt, const int* __restrict__ partial,
                        int* rowptr, int* cursor, int n, int chunk, int etot) {
  int i = blockIdx.x * blockDim.x + threadIdx.x;
  int beg = i * chunk, end = min(n, beg + chunk);
  int run = partial[i];
  for (int j = beg; j < end; ++j) {
    rowptr[j] = run;
    cursor[j] = run;
    run += cnt[j];
  }
  if (i == SCAN_T - 1) rowptr[n] = etot;
}
__global__ void k_scatter(const int* __restrict__ row, const int* __restrict__ col,
                          const float* __restrict__ ea, int* cursor, int2* csr, int e) {
  int i = blockIdx.x * blockDim.x + threadIdx.x;
  if (i < e) {
    int c = col[i];
    int p = atomicAdd(&cursor[c], 1);
    csr[p] = make_int2(row[i], __float_as_int(ea[i]));
  }
}

// ---------------- merged input-only weight prep (linN0 + final W) -----------
// blocks 0-3: linN0 (K=128,N=256, c=0); blocks 4-5: final W (K=64,N=128, c=bb)
__global__ void k_prep0(const float* __restrict__ W1, unsigned short* __restrict__ Wt1,
                        float* __restrict__ cvec1, const float* __restrict__ W2,
                        const float* __restrict__ bin2, unsigned short* __restrict__ Wt2,
                        float* __restrict__ cvec2) {
  int b = blockIdx.x;
  int t = threadIdx.x;
  int cl = t & 63, kq = t >> 6;
  if (b < 4) {
    int col = b * 64 + cl;
#pragma unroll 8
    for (int k = kq * 32; k < kq * 32 + 32; ++k)
      Wt1[col * 128 + k] = f2bf(W1[k * 256 + col]);
    if (kq == 0) cvec1[col] = 0.f;
  } else {
    int col = (b - 4) * 64 + cl;
#pragma unroll 8
    for (int k = kq * 16; k < kq * 16 + 16; ++k)
      Wt2[col * 64 + k] = f2bf(W2[k * 128 + col]);
    if (kq == 0) cvec2[col] = bin2[col];
  }
}

// ---------------- fused BN stats + BN-final + weight fold (last-block) ------
// grid 256 blocks. All blocks: stats into sums via atomics. Last block:
// computes AB and folds W (K=64, N=256) into Wt/cvec.
__global__ void k_bnprep(const unsigned short* __restrict__ x, double* sums, int* done,
                         const float* __restrict__ gamma, const float* __restrict__ beta,
                         const float* __restrict__ W, unsigned short* __restrict__ Wt,
                         float* __restrict__ cvec, int n) {
  int f = threadIdx.x & 63;
  int rt = (blockIdx.x * blockDim.x + threadIdx.x) >> 6;
  int rstride = (gridDim.x * blockDim.x) >> 6;
  double s = 0.0, q = 0.0;
  for (int r = rt; r < n; r += rstride) {
    double v = (double)bf2f(x[(size_t)r * 64 + f]);
    s += v;
    q += v * v;
  }
  __shared__ double ls[256], lq[256];
  ls[threadIdx.x] = s;
  lq[threadIdx.x] = q;
  __syncthreads();
  if (threadIdx.x < 64) {
    s = ls[threadIdx.x] + ls[threadIdx.x + 64] + ls[threadIdx.x + 128] + ls[threadIdx.x + 192];
    q = lq[threadIdx.x] + lq[threadIdx.x + 64] + lq[threadIdx.x + 128] + lq[threadIdx.x + 192];
    atomicAdd(&sums[f], s);
    atomicAdd(&sums[64 + f], q);
    __threadfence();
  }
  __syncthreads();
  __shared__ int lastFlag;
  if (threadIdx.x == 0) {
    int old = atomicAdd(done, 1);
    lastFlag = (old == (int)gridDim.x - 1);
  }
  __syncthreads();
  if (!lastFlag) return;
  // --- last block: BN final + fold ---
  __shared__ float ABl[128];
  if (threadIdx.x < 64) {
    int t = threadIdx.x;
    double mean = atomicAdd(&sums[t], 0.0) / n;        // coherent read
    double qq = atomicAdd(&sums[64 + t], 0.0);
    double var = qq / n - mean * mean;
    float A = gamma[t] * rsqrtf((float)var + BNEPS);
    ABl[t] = A;
    ABl[64 + t] = beta[t] - (float)mean * A;
  }
  __syncthreads();
  int col = threadIdx.x;  // 256 cols
  float c = 0.f;
#pragma unroll 8
  for (int k = 0; k < 64; ++k) {
    float w = W[k * 256 + col];
    Wt[col * 64 + k] = f2bf(ABl[k] * w);
    c = fmaf(ABl[64 + k], w, c);
  }
  cvec[col] = c;
}

// ---------------- MFMA GEMM: h = x @ W' (+c), att scores --------------------
// INBF: bf16 input, double-buffered async gll staging (2-phase pipeline).
template <int K, int CT, bool ATT, bool OB, bool INBF>
__global__ __launch_bounds__(256, 2) void k_gemm(const void* __restrict__ xv,
                                                 const unsigned short* __restrict__ Wt,
                                                 const float* __restrict__ cvec,
                                                 const float* __restrict__ att,
                                                 void* __restrict__ houtv,
                                                 float* __restrict__ s_i,
                                                 float* __restrict__ s_j, int n,
                                                 int ntiles) {
  constexpr int KS = K / 32;
  constexpr int ROWB = 2 * K;
  constexpr int CPR = K / 8;  // 16B chunks per row
  constexpr int NCOL = 4 * CT * 16;
  constexpr int TILEB = 64 * ROWB;
  __shared__ unsigned char xs[(INBF ? 2 : 1) * TILEB];
  const int lane = threadIdx.x & 63;
  const int wv = threadIdx.x >> 6;
  const int l15 = lane & 15;
  const int lq = lane >> 4;
  const int colbase = wv * CT * 16;

  s8v wfr[CT][KS];
#pragma unroll
  for (int ct = 0; ct < CT; ++ct)
#pragma unroll
    for (int ks = 0; ks < KS; ++ks)
      wfr[ct][ks] = *(const s8v*)&Wt[(size_t)(colbase + ct * 16 + l15) * K + ks * 32 + lq * 8];
  float cb[CT][4];
#pragma unroll
  for (int ct = 0; ct < CT; ++ct)
#pragma unroll
    for (int r = 0; r < 4; ++r) cb[ct][r] = cvec[colbase + ct * 16 + lq * 4 + r];
  float ati[ATT ? CT : 1][4], atj[ATT ? CT : 1][4];
  if constexpr (ATT) {
    const float* ar = att + wv * 129;
#pragma unroll
    for (int ct = 0; ct < CT; ++ct)
#pragma unroll
      for (int r = 0; r < 4; ++r) {
        int cc = ct * 16 + lq * 4 + r;
        ati[ct][r] = ar[cc];
        atj[ct][r] = ar[64 + cc];
      }
  }

  auto COMPUTE = [&](const unsigned char* buf, int row0) {
    f4 acc[4][CT];
#pragma unroll
    for (int rt = 0; rt < 4; ++rt)
#pragma unroll
      for (int ct = 0; ct < CT; ++ct) acc[rt][ct] = (f4)0.f;
#pragma unroll
    for (int ks = 0; ks < KS; ++ks) {
      s8v xf[4];
#pragma unroll
      for (int rt = 0; rt < 4; ++rt) {
        int row = rt * 16 + l15;
        int kb = ks * 64 + lq * 16;
        xf[rt] = *(const s8v*)&buf[row * ROWB + (kb ^ ((row & 7) << 4))];
      }
#pragma unroll
      for (int rt = 0; rt < 4; ++rt)
#pragma unroll
        for (int ct = 0; ct < CT; ++ct)
          acc[rt][ct] = __builtin_amdgcn_mfma_f32_16x16x32_bf16(wfr[ct][ks], xf[rt],
                                                                acc[rt][ct], 0, 0, 0);
    }
#pragma unroll
    for (int rt = 0; rt < 4; ++rt) {
      if (row0 + rt * 16 >= n) continue;
      const size_t xrow = (size_t)(row0 + rt * 16 + l15);
      float v[CT][4];
#pragma unroll
      for (int ct = 0; ct < CT; ++ct)
#pragma unroll
        for (int r = 0; r < 4; ++r) v[ct][r] = acc[rt][ct][r] + cb[ct][r];
      if constexpr (OB) {
        float* outp = (float*)houtv;
#pragma unroll
        for (int ct = 0; ct < CT; ++ct) {
          f4 o;
          o[0] = v[ct][0]; o[1] = v[ct][1]; o[2] = v[ct][2]; o[3] = v[ct][3];
          *(f4*)&outp[xrow * NCOL + colbase + ct * 16 + lq * 4] = o;
        }
      } else {
        unsigned short* hout = (unsigned short*)houtv;
#pragma unroll
        for (int ct = 0; ct < CT; ++ct) {
          ushort4 hb4;
          hb4.x = f2bf(v[ct][0]); hb4.y = f2bf(v[ct][1]);
          hb4.z = f2bf(v[ct][2]); hb4.w = f2bf(v[ct][3]);
          *(ushort4*)&hout[xrow * NCOL + colbase + ct * 16 + lq * 4] = hb4;
        }
      }
      if constexpr (ATT) {
        float pi = 0.f, pj = 0.f;
#pragma unroll
        for (int ct = 0; ct < CT; ++ct)
#pragma unroll
          for (int r = 0; r < 4; ++r) {
            pi = fmaf(v[ct][r], ati[ct][r], pi);
            pj = fmaf(v[ct][r], atj[ct][r], pj);
          }
        pi += __shfl_xor(pi, 16, 64); pi += __shfl_xor(pi, 32, 64);
        pj += __shfl_xor(pj, 16, 64); pj += __shfl_xor(pj, 32, 64);
        if (lane < 16) {
          s_i[xrow * 4 + wv] = pi;
          s_j[xrow * 4 + wv] = pj;
        }
      }
    }
  };

  if constexpr (INBF) {
    const unsigned char* xin8 = (const unsigned char*)xv;
    auto STAGE = [&](unsigned char* buf, int t) {
      int row0 = t * 64;
#pragma unroll
      for (int i = 0; i < (64 * CPR) / 256; ++i) {
        int cbase = i * 256 + wv * 64;  // wave-uniform chunk base
        int c = cbase + lane;
        int row = c / CPR, kc = c % CPR;
        int rg = min(row0 + row, n - 1);
        int swz = kc ^ (row & 7);  // matches read-path XOR
        gll16(xin8 + (size_t)rg * ROWB + swz * 16, buf + cbase * 16);
      }
    };
    int cur = 0;
    STAGE(xs, blockIdx.x);  // prologue (grid < ntiles always)
    for (int t = blockIdx.x; t < ntiles; t += gridDim.x) {
      __syncthreads();  // drains vmcnt -> xs[cur] staged; prior reads done
      int tn = t + gridDim.x;
      if (tn < ntiles) STAGE(xs + (cur ^ 1) * TILEB, tn);  // async, overlaps compute
      COMPUTE(xs + cur * TILEB, t * 64);
      cur ^= 1;
    }
  } else {
    for (int t = blockIdx.x; t < ntiles; t += gridDim.x) {
      const int row0 = t * 64;
      __syncthreads();
#pragma unroll
      for (int i = 0; i < (64 * CPR) / 256; ++i) {
        int c = threadIdx.x + i * 256;
        int row = c / CPR, kc = c % CPR;
        int rg = min(row0 + row, n - 1);
        int dst = row * ROWB + ((kc * 16) ^ ((row & 7) << 4));
        const float* xin = (const float*)xv;
        const float* xp = xin + (size_t)rg * K + kc * 8;
        f4 a0 = *(const f4*)xp;
        f4 a1 = *(const f4*)(xp + 4);
        union { s8v v; unsigned short u[8]; } pk;
        pk.u[0] = f2bf(a0[0]); pk.u[1] = f2bf(a0[1]); pk.u[2] = f2bf(a0[2]); pk.u[3] = f2bf(a0[3]);
        pk.u[4] = f2bf(a1[0]); pk.u[5] = f2bf(a1[1]); pk.u[6] = f2bf(a1[2]); pk.u[7] = f2bf(a1[3]);
        *(s8v*)&xs[dst] = pk.v;
      }
      __syncthreads();
      COMPUTE(xs, row0);
    }
  }
}

// ---------------- edge softmax + aggregate (R9-frozen) ----------------------
__global__ __launch_bounds__(256) void k_edge(const int* __restrict__ rowptr,
                                              const int2* __restrict__ csr,
                                              const float* __restrict__ s_i,
                                              const float* __restrict__ s_j,
                                              const unsigned short* __restrict__ hb,
                                              const float* __restrict__ linE,
                                              const float* __restrict__ att,
                                              const float* __restrict__ bias,
                                              unsigned short* __restrict__ xout, int n) {
  __shared__ float lp[4][64][4];
  __shared__ int lsrc[4][64];  // byte offsets into hb
  const unsigned char* hb8 = (const unsigned char*)hb;
  const int lane = threadIdx.x & 63;
  const int wid = threadIdx.x >> 6;
  const int lane8 = lane * 8;
  int v = blockIdx.x * 4 + wid;
  if (v >= n) return;
  v = __builtin_amdgcn_readfirstlane(v);
  const int base = rowptr[v];
  const int deg = rowptr[v + 1] - base;

  const float coef0 = linE[0] * att[0 * 129 + 128];
  const float coef1 = linE[1] * att[1 * 129 + 128];
  const float coef2 = linE[2] * att[2 * 129 + 128];
  const float coef3 = linE[3] * att[3 * 129 + 128];
  const float sj0 = s_j[(size_t)v * 4 + 0];
  const float sj1 = s_j[(size_t)v * 4 + 1];
  const float sj2 = s_j[(size_t)v * 4 + 2];
  const float sj3 = s_j[(size_t)v * 4 + 3];

  auto edge_logits = [&](int i, int& src, float& g0, float& g1, float& g2, float& g3) {
    int2 pk = csr[i];
    src = pk.x;
    float ea = __int_as_float(pk.y);
    f4 siv = *(const f4*)&s_i[(size_t)src * 4];
    g0 = siv[0] + sj0 + ea * coef0; g0 = fmaxf(g0, g0 * NEG);
    g1 = siv[1] + sj1 + ea * coef1; g1 = fmaxf(g1, g1 * NEG);
    g2 = siv[2] + sj2 + ea * coef2; g2 = fmaxf(g2, g2 * NEG);
    g3 = siv[3] + sj3 + ea * coef3; g3 = fmaxf(g3, g3 * NEG);
  };

  const int hd = lane >> 4;
  f4 acc;
  {
    ushort4 hr = *(const ushort4*)(hb8 + ((unsigned)v << 9) + lane8);
    acc[0] = bf2f(hr.x); acc[1] = bf2f(hr.y); acc[2] = bf2f(hr.z); acc[3] = bf2f(hr.w);
  }

  bool fast = (deg <= 64);
  if (fast) {
    float g0 = -INFINITY, g1 = -INFINITY, g2 = -INFINITY, g3 = -INFINITY;
    int src = 0;
    bool valid = lane < deg;
    if (valid) edge_logits(base + lane, src, g0, g1, g2, g3);
    float m0 = wred_max(g0), m1 = wred_max(g1), m2 = wred_max(g2), m3 = wred_max(g3);
    float p0 = valid ? exp2f((g0 - m0) * LOG2E) : 0.f;
    float p1 = valid ? exp2f((g1 - m1) * LOG2E) : 0.f;
    float p2 = valid ? exp2f((g2 - m2) * LOG2E) : 0.f;
    float p3 = valid ? exp2f((g3 - m3) * LOG2E) : 0.f;
    float d0 = wred_sum(p0), d1 = wred_sum(p1), d2 = wred_sum(p2), d3 = wred_sum(p3);
    float rd0 = 1.f / (d0 + 1e-16f);
    float rd1 = 1.f / (d1 + 1e-16f);
    float rd2 = 1.f / (d2 + 1e-16f);
    float rd3 = 1.f / (d3 + 1e-16f);
    if (valid) {
      f4 pp;
      pp[0] = p0 * rd0; pp[1] = p1 * rd1; pp[2] = p2 * rd2; pp[3] = p3 * rd3;
      *(f4*)&lp[wid][lane][0] = pp;
      lsrc[wid][lane] = src << 9;
    }
    for (int e = 0; e < deg; ++e) {
      int off = lsrc[wid][e];
      float a = lp[wid][e][hd];
      ushort4 h0 = *(const ushort4*)(hb8 + (unsigned)(off + lane8));
      acc[0] = fmaf(a, bf2f(h0.x), acc[0]);
      acc[1] = fmaf(a, bf2f(h0.y), acc[1]);
      acc[2] = fmaf(a, bf2f(h0.z), acc[2]);
      acc[3] = fmaf(a, bf2f(h0.w), acc[3]);
    }
  } else {
    float m0 = -INFINITY, m1 = -INFINITY, m2 = -INFINITY, m3 = -INFINITY;
    for (int c0 = 0; c0 < deg; c0 += 64) {
      int i = c0 + lane;
      if (i < deg) {
        int src; float g0, g1, g2, g3;
        edge_logits(base + i, src, g0, g1, g2, g3);
        m0 = fmaxf(m0, g0); m1 = fmaxf(m1, g1); m2 = fmaxf(m2, g2); m3 = fmaxf(m3, g3);
      }
    }
    m0 = wred_max(m0); m1 = wred_max(m1); m2 = wred_max(m2); m3 = wred_max(m3);
    float d0 = 0, d1 = 0, d2 = 0, d3 = 0;
    for (int c0 = 0; c0 < deg; c0 += 64) {
      int i = c0 + lane;
      if (i < deg) {
        int src; float g0, g1, g2, g3;
        edge_logits(base + i, src, g0, g1, g2, g3);
        d0 += exp2f((g0 - m0) * LOG2E);
        d1 += exp2f((g1 - m1) * LOG2E);
        d2 += exp2f((g2 - m2) * LOG2E);
        d3 += exp2f((g3 - m3) * LOG2E);
      }
    }
    d0 = wred_sum(d0); d1 = wred_sum(d1); d2 = wred_sum(d2); d3 = wred_sum(d3);
    float msel = sel4(m0, m1, m2, m3, hd);
    float rdsel = 1.f / (sel4(d0, d1, d2, d3, hd) + 1e-16f);
    const float sjsel = sel4(sj0, sj1, sj2, sj3, hd);
    const float cfsel = sel4(coef0, coef1, coef2, coef3, hd);
    for (int e = base; e < base + deg; ++e) {
      int2 pk = csr[e];
      int src = pk.x;
      float ea = __int_as_float(pk.y);
      f4 siv = *(const f4*)&s_i[(size_t)src * 4];
      float lg = sel4(siv[0], siv[1], siv[2], siv[3], hd) + sjsel + ea * cfsel;
      lg = fmaxf(lg, lg * NEG);
      float a = exp2f((lg - msel) * LOG2E) * rdsel;
      ushort4 hr = *(const ushort4*)(hb8 + ((unsigned)src << 9) + lane8);
      acc[0] = fmaf(a, bf2f(hr.x), acc[0]);
      acc[1] = fmaf(a, bf2f(hr.y), acc[1]);
      acc[2] = fmaf(a, bf2f(hr.z), acc[2]);
      acc[3] = fmaf(a, bf2f(hr.w), acc[3]);
    }
  }
#pragma unroll
  for (int m = 16; m < 64; m <<= 1) {
    acc[0] += __shfl_xor(acc[0], m, 64);
    acc[1] += __shfl_xor(acc[1], m, 64);
    acc[2] += __shfl_xor(acc[2], m, 64);
    acc[3] += __shfl_xor(acc[3], m, 64);
  }
  if (lane < 16) {
    f4 bv = *(const f4*)&bias[lane * 4];
    ushort4 o;
    o.x = f2bf(fmaxf(acc[0] * 0.25f + bv[0], 0.f));
    o.y = f2bf(fmaxf(acc[1] * 0.25f + bv[1], 0.f));
    o.z = f2bf(fmaxf(acc[2] * 0.25f + bv[2], 0.f));
    o.w = f2bf(fmaxf(acc[3] * 0.25f + bv[3], 0.f));
    *(ushort4*)&xout[(size_t)v * 64 + lane * 4] = o;
  }
}

// ---------------- host launch ----------------
extern "C" void kernel_launch(void* const* d_in, const int* in_sizes, int n_in,
                              void* d_out, int out_size, void* d_ws, size_t ws_size,
                              hipStream_t stream) {
  const float* x_in = (const float*)d_in[0];
  const int* ei = (const int*)d_in[1];
  const float* eattr = (const float*)d_in[2];
  const float* linN0 = (const float*)d_in[3];
  const float* linNr = (const float*)d_in[4];
  const float* linE = (const float*)d_in[5];
  const float* attA = (const float*)d_in[6];
  const float* biasA = (const float*)d_in[7];
  const float* bng = (const float*)d_in[8];
  const float* bnb = (const float*)d_in[9];
  const float* W = (const float*)d_in[10];
  const float* bb = (const float*)d_in[11];
  float* out = (float*)d_out;

  const int* row = ei;
  const int* col = ei + EE;

  char* ws = (char*)d_ws;
  size_t o = 0;
  auto alloc = [&](size_t bytes) {
    void* p = ws + o;
    o += (bytes + 255) & ~(size_t)255;
    return p;
  };
  int* cnt = (int*)alloc((size_t)NN * 4);
  int* cursor = (int*)alloc((size_t)NN * 4);
  int* rowptr = (int*)alloc((size_t)(NN + 1) * 4);
  int* partial = (int*)alloc((size_t)SCAN_T * 4);
  int2* csr = (int2*)alloc((size_t)EE * 8);
  unsigned short* h = (unsigned short*)alloc((size_t)NN * 256 * 2);   // bf16
  float* si = (float*)alloc((size_t)NN * 4 * 4);
  float* sj = (float*)alloc((size_t)NN * 4 * 4);
  unsigned short* xa = (unsigned short*)alloc((size_t)NN * 64 * 2);   // bf16
  unsigned short* xb = (unsigned short*)alloc((size_t)NN * 64 * 2);   // bf16
  double* bnsum = (double*)alloc(256 * 8 + 64);  // + done counters
  int* done = (int*)(bnsum + 256);
  unsigned short* Wt = (unsigned short*)alloc((size_t)256 * 128 * 2);
  unsigned short* Wt2 = (unsigned short*)alloc((size_t)128 * 64 * 2);
  float* cvec = (float*)alloc(256 * 4);
  float* cvec2 = (float*)alloc(256 * 4);
  if (o > ws_size) return;

  const int chunk = (NN + SCAN_T - 1) / SCAN_T;
  const int NTILES = (NN + 63) / 64;  // 1563
  const int GG = 512;                  // 2 blocks/CU resident, ~3 tiles each

  hipMemsetAsync(cnt, 0, (size_t)NN * 4, stream);
  hipMemsetAsync(bnsum, 0, 256 * 8 + 64, stream);
  k_count<<<(EE + 255) / 256, 256, 0, stream>>>(col, cnt, EE);
  k_scan1<<<4, 256, 0, stream>>>(cnt, partial, NN, chunk);
  k_scan2<<<1, SCAN_T, 0, stream>>>(partial);
  k_scan3<<<4, 256, 0, stream>>>(cnt, partial, rowptr, cursor, NN, chunk, EE);
  k_scatter<<<(EE + 255) / 256, 256, 0, stream>>>(row, col, eattr, cursor, csr, EE);
  // merged input-only weight prep (linN0 + final W)
  k_prep0<<<6, 256, 0, stream>>>(linN0, Wt, cvec, W, bb, Wt2, cvec2);

  // ---- layer 0 ----
  k_gemm<128, 4, true, false, false><<<GG, 256, 0, stream>>>(x_in, Wt, cvec, attA + 0,
                                                             h, si, sj, NN, NTILES);
  k_edge<<<NN / 4, 256, 0, stream>>>(rowptr, csr, si, sj, h, linE + 0, attA + 0, biasA + 0,
                                     xa, NN);

  // ---- layer 1 ----
  k_bnprep<<<256, 256, 0, stream>>>(xa, bnsum, done + 0, bng, bnb, linNr, Wt, cvec, NN);
  k_gemm<64, 4, true, false, true><<<GG, 256, 0, stream>>>(xa, Wt, cvec, attA + 516,
                                                           h, si, sj, NN, NTILES);
  k_edge<<<NN / 4, 256, 0, stream>>>(rowptr, csr, si, sj, h, linE + 4, attA + 516, biasA + 64,
                                     xb, NN);

  // ---- layer 2 ----
  k_bnprep<<<256, 256, 0, stream>>>(xb, bnsum + 128, done + 1, bng + 64, bnb + 64,
                                    linNr + 64 * 256, Wt, cvec, NN);
  k_gemm<64, 4, true, false, true><<<GG, 256, 0, stream>>>(xb, Wt, cvec, attA + 2 * 516,
                                                           h, si, sj, NN, NTILES);
  k_edge<<<NN / 4, 256, 0, stream>>>(rowptr, csr, si, sj, h, linE + 8, attA + 2 * 516,
                                     biasA + 128, xa, NN);

  // ---- final linear ----
  k_gemm<64, 2, false, true, true><<<GG, 256, 0, stream>>>(xa, Wt2, cvec2, nullptr, out,
                                                           nullptr, nullptr, NN, NTILES);
}